// Round 4
// baseline (156.683 us; speedup 1.0000x reference)
//
#include <hip/hip_runtime.h>

#define NR 4096      // rows per batch
#define DD 512       // feature dim
#define TWO_N 8192

using bf16x8 = __attribute__((ext_vector_type(8))) short;   // 8 bf16 in 4 VGPRs
using f32x4  = __attribute__((ext_vector_type(4))) float;

__device__ __forceinline__ unsigned short f2bf(float f) {
    union { float f; unsigned u; } v; v.f = f;
    unsigned r = v.u + 0x7fff + ((v.u >> 16) & 1);   // round-to-nearest-even
    return (unsigned short)(r >> 16);
}

// Kernel 0: zero the row-sum accumulator S[8192]
__global__ __launch_bounds__(256) void ntx_zero_kernel(float* __restrict__ S) {
    const int i = blockIdx.x * 256 + threadIdx.x;
    if (i < TWO_N) S[i] = 0.f;
}

// Kernel 1: L2-normalize rows of A and B -> bf16 X = [nA; nB], plus fp32 d12[i] = nA_i . nB_i
__global__ __launch_bounds__(256) void ntx_nrm_kernel(const float* __restrict__ A,
                                                      const float* __restrict__ B,
                                                      unsigned short* __restrict__ X,
                                                      float* __restrict__ d12) {
    const int row = blockIdx.x;
    const int t = threadIdx.x;            // 256 threads, 2 elems each
    const int lane = t & 63, wid = t >> 6;

    const float2 av = *(const float2*)(A + row * DD + 2 * t);
    const float2 bv = *(const float2*)(B + row * DD + 2 * t);
    float sa = av.x * av.x + av.y * av.y;
    float sb = bv.x * bv.x + bv.y * bv.y;
#pragma unroll
    for (int o = 32; o; o >>= 1) { sa += __shfl_down(sa, o); sb += __shfl_down(sb, o); }

    __shared__ float red[12];
    if (lane == 0) { red[wid] = sa; red[4 + wid] = sb; }
    __syncthreads();
    const float ta = red[0] + red[1] + red[2] + red[3];
    const float tb = red[4] + red[5] + red[6] + red[7];
    const float ra = 1.f / fmaxf(sqrtf(ta), 1e-8f);
    const float rb = 1.f / fmaxf(sqrtf(tb), 1e-8f);
    const float nax = av.x * ra, nay = av.y * ra;
    const float nbx = bv.x * rb, nby = bv.y * rb;

    *(unsigned*)(X + row * DD + 2 * t) =
        (unsigned)f2bf(nax) | ((unsigned)f2bf(nay) << 16);
    *(unsigned*)(X + (NR + row) * DD + 2 * t) =
        (unsigned)f2bf(nbx) | ((unsigned)f2bf(nby) << 16);

    float dt = nax * nbx + nay * nby;
#pragma unroll
    for (int o = 32; o; o >>= 1) dt += __shfl_down(dt, o);
    if (lane == 0) red[8 + wid] = dt;
    __syncthreads();
    if (t == 0) d12[row] = red[8] + red[9] + red[10] + red[11];
}

// Kernel 2: logits[r,c] = 2 * X_r . Z_c with Z_c = X_{c^4096}; masked exp row-sums -> S[r]
// 128x128 tile, 4 waves (2x2), each wave 64x64 via 4x4 frags of mfma_f32_16x16x32_bf16.
// Staging via global_load_lds width=16 (m97 structure): linear LDS dest, per-lane global src.
__global__ __launch_bounds__(256) void ntx_gemm_lse_kernel(const unsigned short* __restrict__ X,
                                                           float* __restrict__ S) {
    __shared__ unsigned short As[128 * 32];   // flat [row][32] row-major, 8 KB
    __shared__ unsigned short Bs[128 * 32];

    const int t = threadIdx.x;
    const int lane = t & 63, wid = t >> 6;
    const int waveRow = wid >> 1, waveCol = wid & 1;
    const int lr = lane & 15, grp = lane >> 4;
    const int ko = grp * 8;
    const int rowTile = blockIdx.y * 128, colTile = blockIdx.x * 128;

    // staging: wave wid fills 1KB chunks ci=2*wid+q; lane writes LDS bytes ci*1024 + lane*16
    // = element (ci*16 + lane/4)*32 + (lane%4)*8  -> same [128][32] layout the frag reads use
    const int srow0 = lane >> 2;        // 0..15
    const int scol  = (lane & 3) * 8;   // 0,8,16,24

    f32x4 acc[4][4] = {};

    for (int kt = 0; kt < DD; kt += 32) {
        __syncthreads();   // prior reads done before overwrite
#pragma unroll
        for (int q = 0; q < 2; ++q) {
            const int ci = wid * 2 + q;
            const int r  = ci * 16 + srow0;
            unsigned short* la = &As[r * 32 + scol];
            unsigned short* lb = &Bs[r * 32 + scol];
            const unsigned short* ga = X + (size_t)(rowTile + r) * DD + kt + scol;
            const unsigned short* gb = X + (size_t)((colTile + r) ^ NR) * DD + kt + scol;
            __builtin_amdgcn_global_load_lds(
                (const __attribute__((address_space(1))) unsigned*)ga,
                (__attribute__((address_space(3))) unsigned*)la, 16, 0, 0);
            __builtin_amdgcn_global_load_lds(
                (const __attribute__((address_space(1))) unsigned*)gb,
                (__attribute__((address_space(3))) unsigned*)lb, 16, 0, 0);
        }
        __syncthreads();   // vmcnt(0) drain + barrier: tiles ready

        bf16x8 af[4], bfr[4];
#pragma unroll
        for (int m = 0; m < 4; ++m)
            af[m] = *(const bf16x8*)&As[(waveRow * 64 + m * 16 + lr) * 32 + ko];
#pragma unroll
        for (int n = 0; n < 4; ++n)
            bfr[n] = *(const bf16x8*)&Bs[(waveCol * 64 + n * 16 + lr) * 32 + ko];
#pragma unroll
        for (int m = 0; m < 4; ++m)
#pragma unroll
            for (int n = 0; n < 4; ++n)
                acc[m][n] = __builtin_amdgcn_mfma_f32_16x16x32_bf16(af[m], bfr[n], acc[m][n], 0, 0, 0);
    }

    // Epilogue: C/D layout col = lane&15, row = (lane>>4)*4 + reg  (guide §3, m89/m91-verified)
#pragma unroll
    for (int m = 0; m < 4; ++m) {
#pragma unroll
        for (int reg = 0; reg < 4; ++reg) {
            const int R = rowTile + waveRow * 64 + m * 16 + grp * 4 + reg;
            const int maskC = (R + NR) & (TWO_N - 1);
            float rs = 0.f;
#pragma unroll
            for (int n = 0; n < 4; ++n) {
                const int C = colTile + waveCol * 64 + n * 16 + lr;
                const float v = acc[m][n][reg] * 2.0f;   // inv temperature
                rs += (C == maskC) ? 0.f : __expf(v);
            }
            rs += __shfl_xor(rs, 1);
            rs += __shfl_xor(rs, 2);
            rs += __shfl_xor(rs, 4);
            rs += __shfl_xor(rs, 8);
            if (lr == 0) atomicAdd(&S[R], rs);
        }
    }
}

// Kernel 3: loss = mean_r( log(S[r]) - 2*d12[r mod N] ), float32 scalar out.
__global__ __launch_bounds__(256) void ntx_loss_kernel(const float* __restrict__ S,
                                                       const float* __restrict__ d12,
                                                       float* __restrict__ out) {
    const int t = threadIdx.x;
    float a = 0.f;
    for (int r = t; r < TWO_N; r += 256)
        a += __logf(S[r]) - 2.0f * d12[r & (NR - 1)];
    const int lane = t & 63, wid = t >> 6;
#pragma unroll
    for (int o = 32; o; o >>= 1) a += __shfl_down(a, o);
    __shared__ float red[4];
    if (lane == 0) red[wid] = a;
    __syncthreads();
    if (t == 0) out[0] = (red[0] + red[1] + red[2] + red[3]) * (1.f / (float)TWO_N);
}

extern "C" void kernel_launch(void* const* d_in, const int* in_sizes, int n_in,
                              void* d_out, int out_size, void* d_ws, size_t ws_size,
                              hipStream_t stream) {
    const float* A = (const float*)d_in[0];
    const float* B = (const float*)d_in[1];

    // workspace layout
    unsigned short* X = (unsigned short*)d_ws;                    // 8192*512*2 = 8 MB
    float* S   = (float*)((char*)d_ws + (size_t)TWO_N * DD * 2);  // 32 KB
    float* d12 = (float*)((char*)S + (size_t)TWO_N * 4);          // 16 KB

    ntx_zero_kernel<<<TWO_N / 256, 256, 0, stream>>>(S);

    ntx_nrm_kernel<<<NR, 256, 0, stream>>>(A, B, X, d12);

    dim3 grid(TWO_N / 128, TWO_N / 128);
    ntx_gemm_lse_kernel<<<grid, 256, 0, stream>>>(X, S);

    ntx_loss_kernel<<<1, 256, 0, stream>>>(S, d12, (float*)d_out);
}

// Round 5
// 156.339 us; speedup vs baseline: 1.0022x; 1.0022x over previous
//
#include <hip/hip_runtime.h>

#define NR 4096      // rows per batch
#define DD 512       // feature dim
#define TWO_N 8192

using bf16x8 = __attribute__((ext_vector_type(8))) short;   // 8 bf16 in 4 VGPRs
using f32x4  = __attribute__((ext_vector_type(4))) float;

__device__ __forceinline__ unsigned short f2bf(float f) {
    union { float f; unsigned u; } v; v.f = f;
    unsigned r = v.u + 0x7fff + ((v.u >> 16) & 1);   // round-to-nearest-even
    return (unsigned short)(r >> 16);
}

// Kernel 0: zero the row-sum accumulator S[8192]
__global__ __launch_bounds__(256) void ntx_zero_kernel(float* __restrict__ S) {
    const int i = blockIdx.x * 256 + threadIdx.x;
    if (i < TWO_N) S[i] = 0.f;
}

// Kernel 1: L2-normalize rows of A and B -> bf16 X = [nA; nB], plus fp32 d12[i] = nA_i . nB_i
__global__ __launch_bounds__(256) void ntx_nrm_kernel(const float* __restrict__ A,
                                                      const float* __restrict__ B,
                                                      unsigned short* __restrict__ X,
                                                      float* __restrict__ d12) {
    const int row = blockIdx.x;
    const int t = threadIdx.x;            // 256 threads, 2 elems each
    const int lane = t & 63, wid = t >> 6;

    const float2 av = *(const float2*)(A + row * DD + 2 * t);
    const float2 bv = *(const float2*)(B + row * DD + 2 * t);
    float sa = av.x * av.x + av.y * av.y;
    float sb = bv.x * bv.x + bv.y * bv.y;
#pragma unroll
    for (int o = 32; o; o >>= 1) { sa += __shfl_down(sa, o); sb += __shfl_down(sb, o); }

    __shared__ float red[12];
    if (lane == 0) { red[wid] = sa; red[4 + wid] = sb; }
    __syncthreads();
    const float ta = red[0] + red[1] + red[2] + red[3];
    const float tb = red[4] + red[5] + red[6] + red[7];
    const float ra = 1.f / fmaxf(sqrtf(ta), 1e-8f);
    const float rb = 1.f / fmaxf(sqrtf(tb), 1e-8f);
    const float nax = av.x * ra, nay = av.y * ra;
    const float nbx = bv.x * rb, nby = bv.y * rb;

    *(unsigned*)(X + row * DD + 2 * t) =
        (unsigned)f2bf(nax) | ((unsigned)f2bf(nay) << 16);
    *(unsigned*)(X + (NR + row) * DD + 2 * t) =
        (unsigned)f2bf(nbx) | ((unsigned)f2bf(nby) << 16);

    float dt = nax * nbx + nay * nby;
#pragma unroll
    for (int o = 32; o; o >>= 1) dt += __shfl_down(dt, o);
    if (lane == 0) red[8 + wid] = dt;
    __syncthreads();
    if (t == 0) d12[row] = red[8] + red[9] + red[10] + red[11];
}

// Kernel 2: logits[r,c] = 2 * X_r . Z_c with Z_c = X_{c^4096}; masked exp row-sums -> S[r]
// 128x128 tile, 4 waves (2x2), 4x4 frags of mfma_f32_16x16x32_bf16.
// T3-minimum 2-phase: double-buffered LDS, prefetch next K-tile via global_load_lds
// BEFORE computing current, ONE barrier per K-step (load latency hides under compute).
__global__ __launch_bounds__(256) void ntx_gemm_lse_kernel(const unsigned short* __restrict__ X,
                                                           float* __restrict__ S) {
    __shared__ unsigned short As[2][128 * 32];   // 2 x 8 KB, flat [row][32] row-major
    __shared__ unsigned short Bs[2][128 * 32];

    const int t = threadIdx.x;
    const int lane = t & 63, wid = t >> 6;
    const int waveRow = wid >> 1, waveCol = wid & 1;
    const int lr = lane & 15, grp = lane >> 4;
    const int ko = grp * 8;
    const int rowTile = blockIdx.y * 128, colTile = blockIdx.x * 128;

    f32x4 acc[4][4] = {};

    // staging: wave wid fills 1KB chunks ci=2*wid+q; lane writes LDS bytes ci*1024 + lane*16
    // = element (ci*16 + lane/4)*32 + (lane%4)*8 -> linear in lane order (global_load_lds req)
    const int sr = lane >> 2;           // 0..15
    const int sc = (lane & 3) * 8;      // 0,8,16,24

    auto STAGE = [&](int sel, int kt) {
#pragma unroll
        for (int q = 0; q < 2; ++q) {
            const int r = (wid * 2 + q) * 16 + sr;
            __builtin_amdgcn_global_load_lds(
                (const __attribute__((address_space(1))) unsigned*)(X + (size_t)(rowTile + r) * DD + kt + sc),
                (__attribute__((address_space(3))) unsigned*)&As[sel][r * 32 + sc], 16, 0, 0);
            __builtin_amdgcn_global_load_lds(
                (const __attribute__((address_space(1))) unsigned*)(X + (size_t)((colTile + r) ^ NR) * DD + kt + sc),
                (__attribute__((address_space(3))) unsigned*)&Bs[sel][r * 32 + sc], 16, 0, 0);
        }
    };

    auto COMPUTE = [&](int sel) {
        bf16x8 af[4], bfr[4];
#pragma unroll
        for (int m = 0; m < 4; ++m)
            af[m] = *(const bf16x8*)&As[sel][(waveRow * 64 + m * 16 + lr) * 32 + ko];
#pragma unroll
        for (int n = 0; n < 4; ++n)
            bfr[n] = *(const bf16x8*)&Bs[sel][(waveCol * 64 + n * 16 + lr) * 32 + ko];
#pragma unroll
        for (int m = 0; m < 4; ++m)
#pragma unroll
            for (int n = 0; n < 4; ++n)
                acc[m][n] = __builtin_amdgcn_mfma_f32_16x16x32_bf16(af[m], bfr[n], acc[m][n], 0, 0, 0);
    };

    STAGE(0, 0);
    __syncthreads();                    // drains vmcnt(0): buf0 ready
    int cur = 0;
#pragma unroll
    for (int kt = 32; kt < DD; kt += 32) {
        STAGE(cur ^ 1, kt);             // issue next-tile loads (latency hides under compute)
        COMPUTE(cur);
        __syncthreads();                // drains vmcnt(0)+lgkmcnt(0): next buf ready, cur reads done
        cur ^= 1;
    }
    COMPUTE(cur);                       // last tile, no prefetch

    // Epilogue: C/D layout col = lane&15, row = (lane>>4)*4 + reg  (guide §3, m89/m91-verified)
#pragma unroll
    for (int m = 0; m < 4; ++m) {
#pragma unroll
        for (int reg = 0; reg < 4; ++reg) {
            const int R = rowTile + waveRow * 64 + m * 16 + grp * 4 + reg;
            const int maskC = (R + NR) & (TWO_N - 1);
            float rs = 0.f;
#pragma unroll
            for (int n = 0; n < 4; ++n) {
                const int C = colTile + waveCol * 64 + n * 16 + lr;
                const float v = acc[m][n][reg] * 2.0f;   // inv temperature
                rs += (C == maskC) ? 0.f : __expf(v);
            }
            rs += __shfl_xor(rs, 1);
            rs += __shfl_xor(rs, 2);
            rs += __shfl_xor(rs, 4);
            rs += __shfl_xor(rs, 8);
            if (lr == 0) atomicAdd(&S[R], rs);
        }
    }
}

// Kernel 3: loss = mean_r( log(S[r]) - 2*d12[r mod N] ), float32 scalar out.
__global__ __launch_bounds__(256) void ntx_loss_kernel(const float* __restrict__ S,
                                                       const float* __restrict__ d12,
                                                       float* __restrict__ out) {
    const int t = threadIdx.x;
    float a = 0.f;
    for (int r = t; r < TWO_N; r += 256)
        a += __logf(S[r]) - 2.0f * d12[r & (NR - 1)];
    const int lane = t & 63, wid = t >> 6;
#pragma unroll
    for (int o = 32; o; o >>= 1) a += __shfl_down(a, o);
    __shared__ float red[4];
    if (lane == 0) red[wid] = a;
    __syncthreads();
    if (t == 0) out[0] = (red[0] + red[1] + red[2] + red[3]) * (1.f / (float)TWO_N);
}

extern "C" void kernel_launch(void* const* d_in, const int* in_sizes, int n_in,
                              void* d_out, int out_size, void* d_ws, size_t ws_size,
                              hipStream_t stream) {
    const float* A = (const float*)d_in[0];
    const float* B = (const float*)d_in[1];

    // workspace layout
    unsigned short* X = (unsigned short*)d_ws;                    // 8192*512*2 = 8 MB
    float* S   = (float*)((char*)d_ws + (size_t)TWO_N * DD * 2);  // 32 KB
    float* d12 = (float*)((char*)S + (size_t)TWO_N * 4);          // 16 KB

    ntx_zero_kernel<<<TWO_N / 256, 256, 0, stream>>>(S);

    ntx_nrm_kernel<<<NR, 256, 0, stream>>>(A, B, X, d12);

    dim3 grid(TWO_N / 128, TWO_N / 128);
    ntx_gemm_lse_kernel<<<grid, 256, 0, stream>>>(X, S);

    ntx_loss_kernel<<<1, 256, 0, stream>>>(S, d12, (float*)d_out);
}

// Round 6
// 111.801 us; speedup vs baseline: 1.4015x; 1.3984x over previous
//
#include <hip/hip_runtime.h>

#define NR 4096      // rows per batch
#define DD 512       // feature dim
#define TWO_N 8192
#define MT 64        // 8192/128 tiles per dim

using bf16x8 = __attribute__((ext_vector_type(8))) short;   // 8 bf16 in 4 VGPRs
using f32x4  = __attribute__((ext_vector_type(4))) float;

__device__ __forceinline__ unsigned short f2bf(float f) {
    union { float f; unsigned u; } v; v.f = f;
    unsigned r = v.u + 0x7fff + ((v.u >> 16) & 1);   // round-to-nearest-even
    return (unsigned short)(r >> 16);
}

// Kernel 0: zero the row-sum accumulator S[8192]
__global__ __launch_bounds__(256) void ntx_zero_kernel(float* __restrict__ S) {
    const int i = blockIdx.x * 256 + threadIdx.x;
    if (i < TWO_N) S[i] = 0.f;
}

// Kernel 1: L2-normalize rows of A and B -> bf16 X = [nA; nB], plus fp32 d12[i] = nA_i . nB_i
__global__ __launch_bounds__(256) void ntx_nrm_kernel(const float* __restrict__ A,
                                                      const float* __restrict__ B,
                                                      unsigned short* __restrict__ X,
                                                      float* __restrict__ d12) {
    const int row = blockIdx.x;
    const int t = threadIdx.x;            // 256 threads, 2 elems each
    const int lane = t & 63, wid = t >> 6;

    const float2 av = *(const float2*)(A + row * DD + 2 * t);
    const float2 bv = *(const float2*)(B + row * DD + 2 * t);
    float sa = av.x * av.x + av.y * av.y;
    float sb = bv.x * bv.x + bv.y * bv.y;
#pragma unroll
    for (int o = 32; o; o >>= 1) { sa += __shfl_down(sa, o); sb += __shfl_down(sb, o); }

    __shared__ float red[12];
    if (lane == 0) { red[wid] = sa; red[4 + wid] = sb; }
    __syncthreads();
    const float ta = red[0] + red[1] + red[2] + red[3];
    const float tb = red[4] + red[5] + red[6] + red[7];
    const float ra = 1.f / fmaxf(sqrtf(ta), 1e-8f);
    const float rb = 1.f / fmaxf(sqrtf(tb), 1e-8f);
    const float nax = av.x * ra, nay = av.y * ra;
    const float nbx = bv.x * rb, nby = bv.y * rb;

    *(unsigned*)(X + row * DD + 2 * t) =
        (unsigned)f2bf(nax) | ((unsigned)f2bf(nay) << 16);
    *(unsigned*)(X + (NR + row) * DD + 2 * t) =
        (unsigned)f2bf(nbx) | ((unsigned)f2bf(nby) << 16);

    float dt = nax * nbx + nay * nby;
#pragma unroll
    for (int o = 32; o; o >>= 1) dt += __shfl_down(dt, o);
    if (lane == 0) red[8 + wid] = dt;
    __syncthreads();
    if (t == 0) d12[row] = red[8] + red[9] + red[10] + red[11];
}

// Kernel 2: logits[r,c] = 2 * X_r . Z_c, Z_c = X_{c^4096}.
// Symmetry: logits[r,c] = logits[c^N, r^N]. In (u,v)=(i, j^32) tile coords the
// involution is a transpose; compute only u<=v (2080 of 4096 tiles).
//   u<v : no masked entries; scatter exp to S[R] (row sums) AND S[C^N] (mirror rows)
//   u==v: fixed tile (the masked-diagonal band); mask local diagonal, row sums only.
// 128x128 tile, 4 waves (2x2), 4x4 frags of mfma_f32_16x16x32_bf16,
// double-buffered LDS with global_load_lds width=16 staging.
__global__ __launch_bounds__(256) void ntx_gemm_lse_kernel(const unsigned short* __restrict__ X,
                                                           float* __restrict__ S) {
    // ---- linear bid -> upper-triangle (u,v) in 64x64 tile space ----
    const int tb = blockIdx.x;
    // off(u) = u*MT - u*(u-1)/2 ; solve off(u) <= tb < off(u+1)
    const float disc = (float)((2 * MT + 1) * (2 * MT + 1) - 8 * tb);
    int u = (int)(((float)(2 * MT + 1) - sqrtf(disc)) * 0.5f);
    if (u > MT - 1) u = MT - 1;
    if (u < 0) u = 0;
    while (u > 0 && (u * MT - u * (u - 1) / 2) > tb) --u;
    while (((u + 1) * MT - (u + 1) * u / 2) <= tb) ++u;
    const int v = u + (tb - (u * MT - u * (u - 1) / 2));
    const int ti = u, tj = v ^ 32;
    const bool fixedTile = (u == v);
    const int rowTile = ti * 128, colTile = tj * 128;

    __shared__ unsigned short As[2][128 * 32];   // 2 x 8 KB, flat [row][32] row-major
    __shared__ unsigned short Bs[2][128 * 32];

    const int t = threadIdx.x;
    const int lane = t & 63, wid = t >> 6;
    const int waveRow = wid >> 1, waveCol = wid & 1;
    const int lr = lane & 15, grp = lane >> 4;
    const int ko = grp * 8;

    f32x4 acc[4][4] = {};

    // staging: wave wid fills 1KB chunks ci=2*wid+q; lane writes LDS bytes ci*1024 + lane*16
    const int sr = lane >> 2;           // 0..15
    const int sc = (lane & 3) * 8;      // 0,8,16,24

    auto STAGE = [&](int sel, int kt) {
#pragma unroll
        for (int q = 0; q < 2; ++q) {
            const int r = (wid * 2 + q) * 16 + sr;
            __builtin_amdgcn_global_load_lds(
                (const __attribute__((address_space(1))) unsigned*)(X + (size_t)(rowTile + r) * DD + kt + sc),
                (__attribute__((address_space(3))) unsigned*)&As[sel][r * 32 + sc], 16, 0, 0);
            __builtin_amdgcn_global_load_lds(
                (const __attribute__((address_space(1))) unsigned*)(X + (size_t)((colTile + r) ^ NR) * DD + kt + sc),
                (__attribute__((address_space(3))) unsigned*)&Bs[sel][r * 32 + sc], 16, 0, 0);
        }
    };

    auto COMPUTE = [&](int sel) {
        bf16x8 af[4], bfr[4];
#pragma unroll
        for (int m = 0; m < 4; ++m)
            af[m] = *(const bf16x8*)&As[sel][(waveRow * 64 + m * 16 + lr) * 32 + ko];
#pragma unroll
        for (int n = 0; n < 4; ++n)
            bfr[n] = *(const bf16x8*)&Bs[sel][(waveCol * 64 + n * 16 + lr) * 32 + ko];
#pragma unroll
        for (int m = 0; m < 4; ++m)
#pragma unroll
            for (int n = 0; n < 4; ++n)
                acc[m][n] = __builtin_amdgcn_mfma_f32_16x16x32_bf16(af[m], bfr[n], acc[m][n], 0, 0, 0);
    };

    STAGE(0, 0);
    __syncthreads();
    int cur = 0;
#pragma unroll
    for (int kt = 32; kt < DD; kt += 32) {
        STAGE(cur ^ 1, kt);
        COMPUTE(cur);
        __syncthreads();
        cur ^= 1;
    }
    COMPUTE(cur);

    // ---- Epilogue ----
    // C/D layout: col = lane&15 (lr), row = grp*4 + reg.
    // 1) in-place: acc <- exp(2*acc), masked to 0 on fixed-tile local diagonal
#pragma unroll
    for (int m = 0; m < 4; ++m)
#pragma unroll
        for (int n = 0; n < 4; ++n)
#pragma unroll
            for (int reg = 0; reg < 4; ++reg) {
                const int R = rowTile + waveRow * 64 + m * 16 + grp * 4 + reg;
                const int C = colTile + waveCol * 64 + n * 16 + lr;
                const bool masked = fixedTile && (C == (R ^ NR));
                acc[m][n][reg] = masked ? 0.f : __expf(acc[m][n][reg] * 2.0f);
            }

    // 2) row sums -> S[R]
#pragma unroll
    for (int m = 0; m < 4; ++m)
#pragma unroll
        for (int reg = 0; reg < 4; ++reg) {
            float rs = acc[m][0][reg] + acc[m][1][reg] + acc[m][2][reg] + acc[m][3][reg];
            rs += __shfl_xor(rs, 1);
            rs += __shfl_xor(rs, 2);
            rs += __shfl_xor(rs, 4);
            rs += __shfl_xor(rs, 8);
            if (lr == 0) {
                const int R = rowTile + waveRow * 64 + m * 16 + grp * 4 + reg;
                atomicAdd(&S[R], rs);
            }
        }

    // 3) mirror col sums -> S[C^N]  (skip on fixed tiles: they'd double-count)
    if (!fixedTile) {
#pragma unroll
        for (int n = 0; n < 4; ++n) {
            float cs = 0.f;
#pragma unroll
            for (int m = 0; m < 4; ++m)
#pragma unroll
                for (int reg = 0; reg < 4; ++reg)
                    cs += acc[m][n][reg];
            cs += __shfl_xor(cs, 16);
            cs += __shfl_xor(cs, 32);
            if (grp == 0) {
                const int C = colTile + waveCol * 64 + n * 16 + lr;
                atomicAdd(&S[C ^ NR], cs);
            }
        }
    }
}

// Kernel 3: loss = mean_r( log(S[r]) - 2*d12[r mod N] ), float32 scalar out.
__global__ __launch_bounds__(256) void ntx_loss_kernel(const float* __restrict__ S,
                                                       const float* __restrict__ d12,
                                                       float* __restrict__ out) {
    const int t = threadIdx.x;
    float a = 0.f;
    for (int r = t; r < TWO_N; r += 256)
        a += __logf(S[r]) - 2.0f * d12[r & (NR - 1)];
    const int lane = t & 63, wid = t >> 6;
#pragma unroll
    for (int o = 32; o; o >>= 1) a += __shfl_down(a, o);
    __shared__ float red[4];
    if (lane == 0) red[wid] = a;
    __syncthreads();
    if (t == 0) out[0] = (red[0] + red[1] + red[2] + red[3]) * (1.f / (float)TWO_N);
}

extern "C" void kernel_launch(void* const* d_in, const int* in_sizes, int n_in,
                              void* d_out, int out_size, void* d_ws, size_t ws_size,
                              hipStream_t stream) {
    const float* A = (const float*)d_in[0];
    const float* B = (const float*)d_in[1];

    // workspace layout
    unsigned short* X = (unsigned short*)d_ws;                    // 8192*512*2 = 8 MB
    float* S   = (float*)((char*)d_ws + (size_t)TWO_N * DD * 2);  // 32 KB
    float* d12 = (float*)((char*)S + (size_t)TWO_N * 4);          // 16 KB

    ntx_zero_kernel<<<TWO_N / 256, 256, 0, stream>>>(S);

    ntx_nrm_kernel<<<NR, 256, 0, stream>>>(A, B, X, d12);

    const int nTiles = MT * (MT + 1) / 2;   // 2080 upper-triangle tiles
    ntx_gemm_lse_kernel<<<nTiles, 256, 0, stream>>>(X, S);

    ntx_loss_kernel<<<1, 256, 0, stream>>>(S, d12, (float*)d_out);
}

// Round 7
// 104.414 us; speedup vs baseline: 1.5006x; 1.0707x over previous
//
#include <hip/hip_runtime.h>

#define NR 4096      // rows per batch
#define DD 512       // feature dim
#define TWO_N 8192
#define MT 64        // 8192/128 tiles per dim
#define NTILES 2080  // MT*(MT+1)/2
#define CHUNK 260    // NTILES/8 per XCD

using bf16x8 = __attribute__((ext_vector_type(8))) short;   // 8 bf16 in 4 VGPRs
using f32x4  = __attribute__((ext_vector_type(4))) float;

__device__ __forceinline__ unsigned short f2bf(float f) {
    union { float f; unsigned u; } v; v.f = f;
    unsigned r = v.u + 0x7fff + ((v.u >> 16) & 1);   // round-to-nearest-even
    return (unsigned short)(r >> 16);
}

// Kernel 0: zero the row-sum accumulator S[8192]
__global__ __launch_bounds__(256) void ntx_zero_kernel(float* __restrict__ S) {
    const int i = blockIdx.x * 256 + threadIdx.x;
    if (i < TWO_N) S[i] = 0.f;
}

// Kernel 1: L2-normalize rows of A and B -> bf16 X = [nA; nB], plus fp32 d12[i] = nA_i . nB_i
__global__ __launch_bounds__(256) void ntx_nrm_kernel(const float* __restrict__ A,
                                                      const float* __restrict__ B,
                                                      unsigned short* __restrict__ X,
                                                      float* __restrict__ d12) {
    const int row = blockIdx.x;
    const int t = threadIdx.x;            // 256 threads, 2 elems each
    const int lane = t & 63, wid = t >> 6;

    const float2 av = *(const float2*)(A + row * DD + 2 * t);
    const float2 bv = *(const float2*)(B + row * DD + 2 * t);
    float sa = av.x * av.x + av.y * av.y;
    float sb = bv.x * bv.x + bv.y * bv.y;
#pragma unroll
    for (int o = 32; o; o >>= 1) { sa += __shfl_down(sa, o); sb += __shfl_down(sb, o); }

    __shared__ float red[12];
    if (lane == 0) { red[wid] = sa; red[4 + wid] = sb; }
    __syncthreads();
    const float ta = red[0] + red[1] + red[2] + red[3];
    const float tb = red[4] + red[5] + red[6] + red[7];
    const float ra = 1.f / fmaxf(sqrtf(ta), 1e-8f);
    const float rb = 1.f / fmaxf(sqrtf(tb), 1e-8f);
    const float nax = av.x * ra, nay = av.y * ra;
    const float nbx = bv.x * rb, nby = bv.y * rb;

    *(unsigned*)(X + row * DD + 2 * t) =
        (unsigned)f2bf(nax) | ((unsigned)f2bf(nay) << 16);
    *(unsigned*)(X + (NR + row) * DD + 2 * t) =
        (unsigned)f2bf(nbx) | ((unsigned)f2bf(nby) << 16);

    float dt = nax * nbx + nay * nby;
#pragma unroll
    for (int o = 32; o; o >>= 1) dt += __shfl_down(dt, o);
    if (lane == 0) red[8 + wid] = dt;
    __syncthreads();
    if (t == 0) d12[row] = red[8] + red[9] + red[10] + red[11];
}

// Kernel 2: logits[r,c] = 2 * X_r . Z_c, Z_c = X_{c^4096}.
// Symmetry: logits[r,c] = logits[c^N, r^N]; in (u,v)=(i, j^32) tile coords it's a
// transpose. Compute only u<=v (2080 tiles), enumerated SUPERTILE-major (8x8 tile
// supertiles: 28 off-diag x 64 + 8 diag x 36) with XCD-contiguous remap
// (sid = (bid&7)*CHUNK + bid>>3) so each XCD's instantaneous panel set ~2MB < 4MB L2.
__global__ __launch_bounds__(256, 5) void ntx_gemm_lse_kernel(const unsigned short* __restrict__ X,
                                                              float* __restrict__ S) {
    // ---- bid -> XCD-contiguous supertile-ordered sid -> (u,v) ----
    const int bid = blockIdx.x;
    const int sid = (bid & 7) * CHUNK + (bid >> 3);
    int u, v;
    if (sid < 1792) {                    // off-diagonal supertile (U<V): 28 x 64
        const int s = sid >> 6, loc = sid & 63;
        int U = 0;
        while (7 * (U + 1) - (U + 1) * U / 2 <= s) ++U;      // offExcl(U+1) <= s
        const int V = U + 1 + (s - (7 * U - U * (U - 1) / 2));
        u = U * 8 + (loc >> 3);
        v = V * 8 + (loc & 7);
    } else {                             // diagonal supertile (U==V): 8 x 36, lu<=lv
        const int s2 = sid - 1792;
        const int U = s2 / 36, loc = s2 % 36;
        int lu = 0;
        while ((lu + 1) * 8 - (lu + 1) * lu / 2 <= loc) ++lu; // offIncl(lu+1) <= loc
        const int lv = lu + (loc - (lu * 8 - lu * (lu - 1) / 2));
        u = U * 8 + lu;
        v = U * 8 + lv;
    }
    const bool fixedTile = (u == v);
    const int rowTile = u * 128, colTile = (v ^ 32) * 128;

    __shared__ unsigned short As[2][128 * 32];   // 2 x 8 KB, flat [row][32] row-major
    __shared__ unsigned short Bs[2][128 * 32];

    const int t = threadIdx.x;
    const int lane = t & 63, wid = t >> 6;
    const int waveRow = wid >> 1, waveCol = wid & 1;
    const int lr = lane & 15, grp = lane >> 4;
    const int ko = grp * 8;

    f32x4 acc[4][4] = {};

    // staging: wave wid fills 1KB chunks ci=2*wid+q; lane writes LDS bytes ci*1024 + lane*16
    const int sr = lane >> 2;           // 0..15
    const int sc = (lane & 3) * 8;      // 0,8,16,24

    auto STAGE = [&](int sel, int kt) {
#pragma unroll
        for (int q = 0; q < 2; ++q) {
            const int r = (wid * 2 + q) * 16 + sr;
            __builtin_amdgcn_global_load_lds(
                (const __attribute__((address_space(1))) unsigned*)(X + (size_t)(rowTile + r) * DD + kt + sc),
                (__attribute__((address_space(3))) unsigned*)&As[sel][r * 32 + sc], 16, 0, 0);
            __builtin_amdgcn_global_load_lds(
                (const __attribute__((address_space(1))) unsigned*)(X + (size_t)((colTile + r) ^ NR) * DD + kt + sc),
                (__attribute__((address_space(3))) unsigned*)&Bs[sel][r * 32 + sc], 16, 0, 0);
        }
    };

    auto COMPUTE = [&](int sel) {
        bf16x8 af[4], bfr[4];
#pragma unroll
        for (int m = 0; m < 4; ++m)
            af[m] = *(const bf16x8*)&As[sel][(waveRow * 64 + m * 16 + lr) * 32 + ko];
#pragma unroll
        for (int n = 0; n < 4; ++n)
            bfr[n] = *(const bf16x8*)&Bs[sel][(waveCol * 64 + n * 16 + lr) * 32 + ko];
#pragma unroll
        for (int m = 0; m < 4; ++m)
#pragma unroll
            for (int n = 0; n < 4; ++n)
                acc[m][n] = __builtin_amdgcn_mfma_f32_16x16x32_bf16(af[m], bfr[n], acc[m][n], 0, 0, 0);
    };

    STAGE(0, 0);
    __syncthreads();
    int cur = 0;
#pragma unroll
    for (int kt = 32; kt < DD; kt += 32) {
        STAGE(cur ^ 1, kt);
        COMPUTE(cur);
        __syncthreads();
        cur ^= 1;
    }
    COMPUTE(cur);

    // ---- Epilogue ----
    // C/D layout: col = lane&15 (lr), row = grp*4 + reg.
    // 1) in-place: acc <- exp(2*acc), masked to 0 on fixed-tile local diagonal
#pragma unroll
    for (int m = 0; m < 4; ++m)
#pragma unroll
        for (int n = 0; n < 4; ++n)
#pragma unroll
            for (int reg = 0; reg < 4; ++reg) {
                const int R = rowTile + waveRow * 64 + m * 16 + grp * 4 + reg;
                const int C = colTile + waveCol * 64 + n * 16 + lr;
                const bool masked = fixedTile && (C == (R ^ NR));
                acc[m][n][reg] = masked ? 0.f : __expf(acc[m][n][reg] * 2.0f);
            }

    // 2) row sums -> S[R]
#pragma unroll
    for (int m = 0; m < 4; ++m)
#pragma unroll
        for (int reg = 0; reg < 4; ++reg) {
            float rs = acc[m][0][reg] + acc[m][1][reg] + acc[m][2][reg] + acc[m][3][reg];
            rs += __shfl_xor(rs, 1);
            rs += __shfl_xor(rs, 2);
            rs += __shfl_xor(rs, 4);
            rs += __shfl_xor(rs, 8);
            if (lr == 0) {
                const int R = rowTile + waveRow * 64 + m * 16 + grp * 4 + reg;
                atomicAdd(&S[R], rs);
            }
        }

    // 3) mirror col sums -> S[C^N]  (skip on fixed tiles: they'd double-count)
    if (!fixedTile) {
#pragma unroll
        for (int n = 0; n < 4; ++n) {
            float cs = 0.f;
#pragma unroll
            for (int m = 0; m < 4; ++m)
#pragma unroll
                for (int reg = 0; reg < 4; ++reg)
                    cs += acc[m][n][reg];
            cs += __shfl_xor(cs, 16);
            cs += __shfl_xor(cs, 32);
            if (grp == 0) {
                const int C = colTile + waveCol * 64 + n * 16 + lr;
                atomicAdd(&S[C ^ NR], cs);
            }
        }
    }
}

// Kernel 3: loss = mean_r( log(S[r]) - 2*d12[r mod N] ), float32 scalar out.
__global__ __launch_bounds__(256) void ntx_loss_kernel(const float* __restrict__ S,
                                                       const float* __restrict__ d12,
                                                       float* __restrict__ out) {
    const int t = threadIdx.x;
    float a = 0.f;
    for (int r = t; r < TWO_N; r += 256)
        a += __logf(S[r]) - 2.0f * d12[r & (NR - 1)];
    const int lane = t & 63, wid = t >> 6;
#pragma unroll
    for (int o = 32; o; o >>= 1) a += __shfl_down(a, o);
    __shared__ float red[4];
    if (lane == 0) red[wid] = a;
    __syncthreads();
    if (t == 0) out[0] = (red[0] + red[1] + red[2] + red[3]) * (1.f / (float)TWO_N);
}

extern "C" void kernel_launch(void* const* d_in, const int* in_sizes, int n_in,
                              void* d_out, int out_size, void* d_ws, size_t ws_size,
                              hipStream_t stream) {
    const float* A = (const float*)d_in[0];
    const float* B = (const float*)d_in[1];

    // workspace layout
    unsigned short* X = (unsigned short*)d_ws;                    // 8192*512*2 = 8 MB
    float* S   = (float*)((char*)d_ws + (size_t)TWO_N * DD * 2);  // 32 KB
    float* d12 = (float*)((char*)S + (size_t)TWO_N * 4);          // 16 KB

    ntx_zero_kernel<<<TWO_N / 256, 256, 0, stream>>>(S);

    ntx_nrm_kernel<<<NR, 256, 0, stream>>>(A, B, X, d12);

    ntx_gemm_lse_kernel<<<NTILES, 256, 0, stream>>>(X, S);

    ntx_loss_kernel<<<1, 256, 0, stream>>>(S, d12, (float*)d_out);
}

// Round 8
// 87.015 us; speedup vs baseline: 1.8007x; 1.2000x over previous
//
#include <hip/hip_runtime.h>

#define NR 4096      // rows per batch
#define DD 512       // feature dim
#define TWO_N 8192
#define MT 64        // 8192/128 tiles per dim
#define NTILES 2080  // MT*(MT+1)/2
#define CHUNK 260    // NTILES/8 per XCD

using bf16x8 = __attribute__((ext_vector_type(8))) short;   // 8 bf16 in 4 VGPRs
using f32x4  = __attribute__((ext_vector_type(4))) float;

__device__ __forceinline__ unsigned short f2bf(float f) {
    union { float f; unsigned u; } v; v.f = f;
    unsigned r = v.u + 0x7fff + ((v.u >> 16) & 1);   // round-to-nearest-even
    return (unsigned short)(r >> 16);
}

// Kernel 1: L2-normalize rows of A and B -> bf16 X = [nA; nB], fp32 d12[i] = nA_i . nB_i.
// Also zeroes S[8192] (2 elements per block) - saves a separate launch.
__global__ __launch_bounds__(256) void ntx_nrm_kernel(const float* __restrict__ A,
                                                      const float* __restrict__ B,
                                                      unsigned short* __restrict__ X,
                                                      float* __restrict__ d12,
                                                      float* __restrict__ S) {
    const int row = blockIdx.x;
    const int t = threadIdx.x;            // 256 threads, 2 elems each
    const int lane = t & 63, wid = t >> 6;

    if (t < 2) S[row * 2 + t] = 0.f;

    const float2 av = *(const float2*)(A + row * DD + 2 * t);
    const float2 bv = *(const float2*)(B + row * DD + 2 * t);
    float sa = av.x * av.x + av.y * av.y;
    float sb = bv.x * bv.x + bv.y * bv.y;
#pragma unroll
    for (int o = 32; o; o >>= 1) { sa += __shfl_down(sa, o); sb += __shfl_down(sb, o); }

    __shared__ float red[12];
    if (lane == 0) { red[wid] = sa; red[4 + wid] = sb; }
    __syncthreads();
    const float ta = red[0] + red[1] + red[2] + red[3];
    const float tb = red[4] + red[5] + red[6] + red[7];
    const float ra = 1.f / fmaxf(sqrtf(ta), 1e-8f);
    const float rb = 1.f / fmaxf(sqrtf(tb), 1e-8f);
    const float nax = av.x * ra, nay = av.y * ra;
    const float nbx = bv.x * rb, nby = bv.y * rb;

    *(unsigned*)(X + row * DD + 2 * t) =
        (unsigned)f2bf(nax) | ((unsigned)f2bf(nay) << 16);
    *(unsigned*)(X + (NR + row) * DD + 2 * t) =
        (unsigned)f2bf(nbx) | ((unsigned)f2bf(nby) << 16);

    float dt = nax * nbx + nay * nby;
#pragma unroll
    for (int o = 32; o; o >>= 1) dt += __shfl_down(dt, o);
    if (lane == 0) red[8 + wid] = dt;
    __syncthreads();
    if (t == 0) d12[row] = red[8] + red[9] + red[10] + red[11];
}

// Kernel 2: logits[r,c] = 2 * X_r . Z_c, Z_c = X_{c^4096}.
// Symmetry: compute only u<=v in (u,v)=(i, j^32) tile coords (2080 tiles),
// supertile-major enumeration + XCD-contiguous remap (L2 locality, round-7 verified).
// NEW: counted-vmcnt pipeline (T4): 2-deep prefetch, raw s_barrier, per-wave
// s_waitcnt vmcnt(4) - loads stay in flight across barriers, never drained to 0.
__global__ __launch_bounds__(256) void ntx_gemm_lse_kernel(const unsigned short* __restrict__ X,
                                                           float* __restrict__ S) {
    // ---- bid -> XCD-contiguous supertile-ordered sid -> (u,v) ----
    const int bid = blockIdx.x;
    const int sid = (bid & 7) * CHUNK + (bid >> 3);
    int u, v;
    if (sid < 1792) {                    // off-diagonal supertile (U<V): 28 x 64
        const int s = sid >> 6, loc = sid & 63;
        int U = 0;
        while (7 * (U + 1) - (U + 1) * U / 2 <= s) ++U;      // offExcl(U+1) <= s
        const int V = U + 1 + (s - (7 * U - U * (U - 1) / 2));
        u = U * 8 + (loc >> 3);
        v = V * 8 + (loc & 7);
    } else {                             // diagonal supertile (U==V): 8 x 36, lu<=lv
        const int s2 = sid - 1792;
        const int U = s2 / 36, loc = s2 % 36;
        int lu = 0;
        while ((lu + 1) * 8 - (lu + 1) * lu / 2 <= loc) ++lu; // offIncl(lu+1) <= loc
        const int lv = lu + (loc - (lu * 8 - lu * (lu - 1) / 2));
        u = U * 8 + lu;
        v = U * 8 + lv;
    }
    const bool fixedTile = (u == v);
    const int rowTile = u * 128, colTile = (v ^ 32) * 128;

    __shared__ unsigned short As[2][128 * 32];   // 2 x 8 KB, flat [row][32] row-major
    __shared__ unsigned short Bs[2][128 * 32];

    const int t = threadIdx.x;
    const int lane = t & 63, wid = t >> 6;
    const int waveRow = wid >> 1, waveCol = wid & 1;
    const int lr = lane & 15, grp = lane >> 4;
    const int ko = grp * 8;

    f32x4 acc[4][4] = {};

    // staging: wave wid fills 1KB chunks ci=2*wid+q; lane writes LDS bytes ci*1024 + lane*16
    const int sr = lane >> 2;           // 0..15
    const int sc = (lane & 3) * 8;      // 0,8,16,24

    auto STAGE = [&](int sel, int kt) { // 4 VMEM instructions per wave
#pragma unroll
        for (int q = 0; q < 2; ++q) {
            const int r = (wid * 2 + q) * 16 + sr;
            __builtin_amdgcn_global_load_lds(
                (const __attribute__((address_space(1))) unsigned*)(X + (size_t)(rowTile + r) * DD + kt + sc),
                (__attribute__((address_space(3))) unsigned*)&As[sel][r * 32 + sc], 16, 0, 0);
            __builtin_amdgcn_global_load_lds(
                (const __attribute__((address_space(1))) unsigned*)(X + (size_t)((colTile + r) ^ NR) * DD + kt + sc),
                (__attribute__((address_space(3))) unsigned*)&Bs[sel][r * 32 + sc], 16, 0, 0);
        }
    };

    auto COMPUTE = [&](int sel) {
        bf16x8 af[4], bfr[4];
#pragma unroll
        for (int m = 0; m < 4; ++m)
            af[m] = *(const bf16x8*)&As[sel][(waveRow * 64 + m * 16 + lr) * 32 + ko];
#pragma unroll
        for (int n = 0; n < 4; ++n)
            bfr[n] = *(const bf16x8*)&Bs[sel][(waveCol * 64 + n * 16 + lr) * 32 + ko];
#pragma unroll
        for (int m = 0; m < 4; ++m)
#pragma unroll
            for (int n = 0; n < 4; ++n)
                acc[m][n] = __builtin_amdgcn_mfma_f32_16x16x32_bf16(af[m], bfr[n], acc[m][n], 0, 0, 0);
    };

    // ---- 2-deep counted-vmcnt pipeline over 16 K-tiles ----
    STAGE(0, 0);                        // 4 outstanding (buf0)
    STAGE(1, 32);                       // 8 outstanding (buf0+buf1)
#pragma unroll
    for (int i = 0; i < 16; ++i) {
        const int cur = i & 1;
        if (i < 15) asm volatile("s_waitcnt vmcnt(4)" ::: "memory");  // my buf[cur] loads done
        else        asm volatile("s_waitcnt vmcnt(0)" ::: "memory");  // tail
        __builtin_amdgcn_s_barrier();   // all waves' buf[cur] writes landed
        COMPUTE(cur);
        if (i < 14) {
            asm volatile("s_waitcnt lgkmcnt(0)" ::: "memory");        // my ds_reads of buf[cur] done
            __builtin_amdgcn_s_barrier();                             // everyone's done reading buf[cur]
            STAGE(cur, (i + 2) * 32);   // refill 2 ahead; back to 8 outstanding
        }
    }

    // ---- Epilogue ----
    // C/D layout: col = lane&15 (lr), row = grp*4 + reg.
    // 1) in-place: acc <- exp(2*acc), masked to 0 on fixed-tile local diagonal
#pragma unroll
    for (int m = 0; m < 4; ++m)
#pragma unroll
        for (int n = 0; n < 4; ++n)
#pragma unroll
            for (int reg = 0; reg < 4; ++reg) {
                const int R = rowTile + waveRow * 64 + m * 16 + grp * 4 + reg;
                const int C = colTile + waveCol * 64 + n * 16 + lr;
                const bool masked = fixedTile && (C == (R ^ NR));
                acc[m][n][reg] = masked ? 0.f : __expf(acc[m][n][reg] * 2.0f);
            }

    // 2) row sums -> S[R]
#pragma unroll
    for (int m = 0; m < 4; ++m)
#pragma unroll
        for (int reg = 0; reg < 4; ++reg) {
            float rs = acc[m][0][reg] + acc[m][1][reg] + acc[m][2][reg] + acc[m][3][reg];
            rs += __shfl_xor(rs, 1);
            rs += __shfl_xor(rs, 2);
            rs += __shfl_xor(rs, 4);
            rs += __shfl_xor(rs, 8);
            if (lr == 0) {
                const int R = rowTile + waveRow * 64 + m * 16 + grp * 4 + reg;
                atomicAdd(&S[R], rs);
            }
        }

    // 3) mirror col sums -> S[C^N]  (skip on fixed tiles: they'd double-count)
    if (!fixedTile) {
#pragma unroll
        for (int n = 0; n < 4; ++n) {
            float cs = 0.f;
#pragma unroll
            for (int m = 0; m < 4; ++m)
#pragma unroll
                for (int reg = 0; reg < 4; ++reg)
                    cs += acc[m][n][reg];
            cs += __shfl_xor(cs, 16);
            cs += __shfl_xor(cs, 32);
            if (grp == 0) {
                const int C = colTile + waveCol * 64 + n * 16 + lr;
                atomicAdd(&S[C ^ NR], cs);
            }
        }
    }
}

// Kernel 3: loss = mean_r( log(S[r]) - 2*d12[r mod N] ), float32 scalar out.
__global__ __launch_bounds__(256) void ntx_loss_kernel(const float* __restrict__ S,
                                                       const float* __restrict__ d12,
                                                       float* __restrict__ out) {
    const int t = threadIdx.x;
    float a = 0.f;
    for (int r = t; r < TWO_N; r += 256)
        a += __logf(S[r]) - 2.0f * d12[r & (NR - 1)];
    const int lane = t & 63, wid = t >> 6;
#pragma unroll
    for (int o = 32; o; o >>= 1) a += __shfl_down(a, o);
    __shared__ float red[4];
    if (lane == 0) red[wid] = a;
    __syncthreads();
    if (t == 0) out[0] = (red[0] + red[1] + red[2] + red[3]) * (1.f / (float)TWO_N);
}

extern "C" void kernel_launch(void* const* d_in, const int* in_sizes, int n_in,
                              void* d_out, int out_size, void* d_ws, size_t ws_size,
                              hipStream_t stream) {
    const float* A = (const float*)d_in[0];
    const float* B = (const float*)d_in[1];

    // workspace layout
    unsigned short* X = (unsigned short*)d_ws;                    // 8192*512*2 = 8 MB
    float* S   = (float*)((char*)d_ws + (size_t)TWO_N * DD * 2);  // 32 KB
    float* d12 = (float*)((char*)S + (size_t)TWO_N * 4);          // 16 KB

    ntx_nrm_kernel<<<NR, 256, 0, stream>>>(A, B, X, d12, S);

    ntx_gemm_lse_kernel<<<NTILES, 256, 0, stream>>>(X, S);

    ntx_loss_kernel<<<1, 256, 0, stream>>>(S, d12, (float*)d_out);
}

// Round 9
// 81.558 us; speedup vs baseline: 1.9211x; 1.0669x over previous
//
#include <hip/hip_runtime.h>

#define NR 4096      // rows per batch
#define DD 512       // feature dim
#define TWO_N 8192
#define MT 64        // 8192/128 tiles per dim
#define NTILES 2080  // MT*(MT+1)/2
#define CHUNK 260    // NTILES/8 per XCD

using bf16x8 = __attribute__((ext_vector_type(8))) short;   // 8 bf16 in 4 VGPRs
using f32x4  = __attribute__((ext_vector_type(4))) float;

__device__ __forceinline__ unsigned short f2bf(float f) {
    union { float f; unsigned u; } v; v.f = f;
    unsigned r = v.u + 0x7fff + ((v.u >> 16) & 1);   // round-to-nearest-even
    return (unsigned short)(r >> 16);
}

// Kernel 1: L2-normalize rows of A and B -> bf16 X = [nA; nB], fp32 d12[i] = nA_i . nB_i.
// Also zeroes S[8192] (2 elements per block).
__global__ __launch_bounds__(256) void ntx_nrm_kernel(const float* __restrict__ A,
                                                      const float* __restrict__ B,
                                                      unsigned short* __restrict__ X,
                                                      float* __restrict__ d12,
                                                      float* __restrict__ S) {
    const int row = blockIdx.x;
    const int t = threadIdx.x;            // 256 threads, 2 elems each
    const int lane = t & 63, wid = t >> 6;

    if (t < 2) S[row * 2 + t] = 0.f;

    const float2 av = *(const float2*)(A + row * DD + 2 * t);
    const float2 bv = *(const float2*)(B + row * DD + 2 * t);
    float sa = av.x * av.x + av.y * av.y;
    float sb = bv.x * bv.x + bv.y * bv.y;
#pragma unroll
    for (int o = 32; o; o >>= 1) { sa += __shfl_down(sa, o); sb += __shfl_down(sb, o); }

    __shared__ float red[12];
    if (lane == 0) { red[wid] = sa; red[4 + wid] = sb; }
    __syncthreads();
    const float ta = red[0] + red[1] + red[2] + red[3];
    const float tb = red[4] + red[5] + red[6] + red[7];
    const float ra = 1.f / fmaxf(sqrtf(ta), 1e-8f);
    const float rb = 1.f / fmaxf(sqrtf(tb), 1e-8f);
    const float nax = av.x * ra, nay = av.y * ra;
    const float nbx = bv.x * rb, nby = bv.y * rb;

    *(unsigned*)(X + row * DD + 2 * t) =
        (unsigned)f2bf(nax) | ((unsigned)f2bf(nay) << 16);
    *(unsigned*)(X + (NR + row) * DD + 2 * t) =
        (unsigned)f2bf(nbx) | ((unsigned)f2bf(nby) << 16);

    float dt = nax * nbx + nay * nby;
#pragma unroll
    for (int o = 32; o; o >>= 1) dt += __shfl_down(dt, o);
    if (lane == 0) red[8 + wid] = dt;
    __syncthreads();
    if (t == 0) d12[row] = red[8] + red[9] + red[10] + red[11];
}

// Kernel 2: logits[r,c] = 2 * X_r . Z_c, Z_c = X_{c^4096}.
// Symmetry: compute only u<=v in (u,v)=(i, j^32) tile coords (2080 tiles),
// supertile-major + XCD-contiguous remap (round-7 verified).
// Round-9: BK=64 LDS tiles ([128 rows][64 bf16] = 128B rows) with 3-bit XOR swizzle
// slot_phys = slot ^ (row&7): conflict-free ds_read_b128 (rule-21 both-sides:
// linear LDS dest + inverse-swizzled GLOBAL source + swizzled read).
// Counted-vmcnt 2-deep pipeline kept (round-8 verified).
__global__ __launch_bounds__(256) void ntx_gemm_lse_kernel(const unsigned short* __restrict__ X,
                                                           float* __restrict__ S) {
    // ---- bid -> XCD-contiguous supertile-ordered sid -> (u,v) ----
    const int bid = blockIdx.x;
    const int sid = (bid & 7) * CHUNK + (bid >> 3);
    int u, v;
    if (sid < 1792) {                    // off-diagonal supertile (U<V): 28 x 64
        const int s = sid >> 6, loc = sid & 63;
        int U = 0;
        while (7 * (U + 1) - (U + 1) * U / 2 <= s) ++U;      // offExcl(U+1) <= s
        const int V = U + 1 + (s - (7 * U - U * (U - 1) / 2));
        u = U * 8 + (loc >> 3);
        v = V * 8 + (loc & 7);
    } else {                             // diagonal supertile (U==V): 8 x 36, lu<=lv
        const int s2 = sid - 1792;
        const int U = s2 / 36, loc = s2 % 36;
        int lu = 0;
        while ((lu + 1) * 8 - (lu + 1) * lu / 2 <= loc) ++lu; // offIncl(lu+1) <= loc
        const int lv = lu + (loc - (lu * 8 - lu * (lu - 1) / 2));
        u = U * 8 + lu;
        v = U * 8 + lv;
    }
    const bool fixedTile = (u == v);
    const int rowTile = u * 128, colTile = (v ^ 32) * 128;

    __shared__ unsigned short As[2][128 * 64];   // 2 x 16 KB
    __shared__ unsigned short Bs[2][128 * 64];

    const int t = threadIdx.x;
    const int lane = t & 63, wid = t >> 6;
    const int waveRow = wid >> 1, waveCol = wid & 1;
    const int lr = lane & 15, grp = lane >> 4;
    const int r3 = lr & 7;               // row&7 of every fragment row this lane reads

    f32x4 acc[4][4] = {};

    // staging: wave wid fills 1KB chunks ci=wid*4+q (8 rows of 128B each).
    // lane l writes LDS bytes ci*1024 + l*16  -> physical (row = ci*8 + l/8, slot = l&7).
    // inverse source swizzle: physical slot p at row r must hold global slot p^(r&7);
    // here r&7 = (l>>3)&7, so source col = kt + ((l&7) ^ ((l>>3)&7)) * 8 elems.
    const int srow = lane >> 3;                       // 0..7 within chunk
    const int scol = ((lane & 7) ^ srow) * 8;         // swizzled source col (elems)

    auto STAGE = [&](int sel, int kt) {  // 8 VMEM instructions per wave
#pragma unroll
        for (int q = 0; q < 4; ++q) {
            const int ci = wid * 4 + q;
            const int r  = ci * 8 + srow;
            const int lo = ci * 512 + lane * 8;       // ushort index of lane's 16B slot
            __builtin_amdgcn_global_load_lds(
                (const __attribute__((address_space(1))) unsigned*)(X + (size_t)(rowTile + r) * DD + kt + scol),
                (__attribute__((address_space(3))) unsigned*)&As[sel][lo], 16, 0, 0);
            __builtin_amdgcn_global_load_lds(
                (const __attribute__((address_space(1))) unsigned*)(X + (size_t)((colTile + r) ^ NR) * DD + kt + scol),
                (__attribute__((address_space(3))) unsigned*)&Bs[sel][lo], 16, 0, 0);
        }
    };

    auto COMPUTE = [&](int sel) {
#pragma unroll
        for (int kk = 0; kk < 2; ++kk) {
            bf16x8 af[4], bfr[4];
#pragma unroll
            for (int m = 0; m < 4; ++m)
                af[m] = *(const bf16x8*)&As[sel][(waveRow * 64 + m * 16 + lr) * 64 +
                                                 (((kk * 4 + grp) ^ r3) * 8)];
#pragma unroll
            for (int n = 0; n < 4; ++n)
                bfr[n] = *(const bf16x8*)&Bs[sel][(waveCol * 64 + n * 16 + lr) * 64 +
                                                  (((kk * 4 + grp) ^ r3) * 8)];
#pragma unroll
            for (int m = 0; m < 4; ++m)
#pragma unroll
                for (int n = 0; n < 4; ++n)
                    acc[m][n] = __builtin_amdgcn_mfma_f32_16x16x32_bf16(af[m], bfr[n], acc[m][n], 0, 0, 0);
        }
    };

    // ---- 2-deep counted-vmcnt pipeline over 8 K-tiles (BK=64) ----
    STAGE(0, 0);                        // 8 outstanding (buf0)
    STAGE(1, 64);                       // 16 outstanding (buf0+buf1)
#pragma unroll
    for (int i = 0; i < 8; ++i) {
        const int cur = i & 1;
        if (i < 7) asm volatile("s_waitcnt vmcnt(8)" ::: "memory");   // my buf[cur] loads done
        else       asm volatile("s_waitcnt vmcnt(0)" ::: "memory");   // tail
        __builtin_amdgcn_s_barrier();   // all waves' buf[cur] writes landed
        COMPUTE(cur);
        if (i < 6) {
            asm volatile("s_waitcnt lgkmcnt(0)" ::: "memory");        // my ds_reads of buf[cur] done
            __builtin_amdgcn_s_barrier();                             // everyone's done reading buf[cur]
            STAGE(cur, (i + 2) * 64);   // refill 2 ahead; back to 16 outstanding
        }
    }

    // ---- Epilogue ----
    // C/D layout: col = lane&15 (lr), row = grp*4 + reg.
    // 1) in-place: acc <- exp(2*acc), masked to 0 on fixed-tile local diagonal
#pragma unroll
    for (int m = 0; m < 4; ++m)
#pragma unroll
        for (int n = 0; n < 4; ++n)
#pragma unroll
            for (int reg = 0; reg < 4; ++reg) {
                const int R = rowTile + waveRow * 64 + m * 16 + grp * 4 + reg;
                const int C = colTile + waveCol * 64 + n * 16 + lr;
                const bool masked = fixedTile && (C == (R ^ NR));
                acc[m][n][reg] = masked ? 0.f : __expf(acc[m][n][reg] * 2.0f);
            }

    // 2) row sums -> S[R]
#pragma unroll
    for (int m = 0; m < 4; ++m)
#pragma unroll
        for (int reg = 0; reg < 4; ++reg) {
            float rs = acc[m][0][reg] + acc[m][1][reg] + acc[m][2][reg] + acc[m][3][reg];
            rs += __shfl_xor(rs, 1);
            rs += __shfl_xor(rs, 2);
            rs += __shfl_xor(rs, 4);
            rs += __shfl_xor(rs, 8);
            if (lr == 0) {
                const int R = rowTile + waveRow * 64 + m * 16 + grp * 4 + reg;
                atomicAdd(&S[R], rs);
            }
        }

    // 3) mirror col sums -> S[C^N]  (skip on fixed tiles: they'd double-count)
    if (!fixedTile) {
#pragma unroll
        for (int n = 0; n < 4; ++n) {
            float cs = 0.f;
#pragma unroll
            for (int m = 0; m < 4; ++m)
#pragma unroll
                for (int reg = 0; reg < 4; ++reg)
                    cs += acc[m][n][reg];
            cs += __shfl_xor(cs, 16);
            cs += __shfl_xor(cs, 32);
            if (grp == 0) {
                const int C = colTile + waveCol * 64 + n * 16 + lr;
                atomicAdd(&S[C ^ NR], cs);
            }
        }
    }
}

// Kernel 3: loss = mean_r( log(S[r]) - 2*d12[r mod N] ), float32 scalar out.
__global__ __launch_bounds__(256) void ntx_loss_kernel(const float* __restrict__ S,
                                                       const float* __restrict__ d12,
                                                       float* __restrict__ out) {
    const int t = threadIdx.x;
    float a = 0.f;
    for (int r = t; r < TWO_N; r += 256)
        a += __logf(S[r]) - 2.0f * d12[r & (NR - 1)];
    const int lane = t & 63, wid = t >> 6;
#pragma unroll
    for (int o = 32; o; o >>= 1) a += __shfl_down(a, o);
    __shared__ float red[4];
    if (lane == 0) red[wid] = a;
    __syncthreads();
    if (t == 0) out[0] = (red[0] + red[1] + red[2] + red[3]) * (1.f / (float)TWO_N);
}

extern "C" void kernel_launch(void* const* d_in, const int* in_sizes, int n_in,
                              void* d_out, int out_size, void* d_ws, size_t ws_size,
                              hipStream_t stream) {
    const float* A = (const float*)d_in[0];
    const float* B = (const float*)d_in[1];

    // workspace layout
    unsigned short* X = (unsigned short*)d_ws;                    // 8192*512*2 = 8 MB
    float* S   = (float*)((char*)d_ws + (size_t)TWO_N * DD * 2);  // 32 KB
    float* d12 = (float*)((char*)S + (size_t)TWO_N * 4);          // 16 KB

    ntx_nrm_kernel<<<NR, 256, 0, stream>>>(A, B, X, d12, S);

    ntx_gemm_lse_kernel<<<NTILES, 256, 0, stream>>>(X, S);

    ntx_loss_kernel<<<1, 256, 0, stream>>>(S, d12, (float*)d_out);
}